// Round 12
// baseline (151.327 us; speedup 1.0000x reference)
//
#include <hip/hip_runtime.h>
#include <math.h>

// Problem constants
#define Bsz   16
#define Lseq  512
#define Nfeat 32
#define E     128
#define EMB   8
#define FCH   64
#define Hd    256
#define PRE   96
#define M     16384   // N*L
#define MH    8193
#define LAMBDA 0.01f

// workspace layout (float offsets)
#define OFF_CS  0          // 8193*16 -> 131088 floats
#define OFF_P   131088     // P[f1g][b][k]: 32*16*1024 = 524288 floats
// total = 655376 floats = 2.6 MB

#define REV_M   6.103515625e-5f    // 1/16384 (angle in revolutions)
#define REV_128 7.8125e-3f         // 1/128

__device__ __forceinline__ float sin_rev(float r) { return __builtin_amdgcn_sinf(r); }
__device__ __forceinline__ float cos_rev(float r) { return __builtin_amdgcn_cosf(r); }

// ---------------- kernel 1: C/S tables only ----------------
// C[f,m]+iS[f,m] = wf * sum_t trig(2pi f t/M) emb10[t,m]
__global__ __launch_bounds__(256, 4)
void k_cs(const float* __restrict__ emb10, float* __restrict__ ws) {
  __shared__ float e10T[Lseq * EMB];    // transposed [m][t], conflict-free reads
  int bid = blockIdx.x, tid = threadIdx.x;
  for (int j = tid; j < Lseq * EMB; j += 256) {
    int t = j >> 3, m = j & 7;
    e10T[m * 512 + t] = emb10[j];       // coalesced global read
  }
  __syncthreads();
  int floc = tid >> 5, tl = tid & 31;
  #pragma unroll
  for (int ff = 0; ff < 4; ++ff) {
    int f = bid * 32 + ff * 8 + floc;   // grid 256 -> f in 0..8191
    float ca[EMB], sa[EMB];
    #pragma unroll
    for (int m = 0; m < EMB; ++m) { ca[m] = 0.f; sa[m] = 0.f; }
    #pragma unroll 4
    for (int it = 0; it < 16; ++it) {
      int t = tl + 32 * it;
      int k = (f * t) & (M - 1);
      float rv = (float)k * REV_M;
      float cc = cos_rev(rv), ss = sin_rev(rv);
      #pragma unroll
      for (int m = 0; m < EMB; ++m) {
        float ev = e10T[m * 512 + t];   // bank = t%32 = tl -> conflict-free
        ca[m] = fmaf(cc, ev, ca[m]);
        sa[m] = fmaf(ss, ev, sa[m]);
      }
    }
    #pragma unroll
    for (int off = 16; off >= 1; off >>= 1) {
      #pragma unroll
      for (int m = 0; m < EMB; ++m) {
        ca[m] += __shfl_xor(ca[m], off, 64);
        sa[m] += __shfl_xor(sa[m], off, 64);
      }
    }
    if (tl == 0) {
      float wf = (f == 0) ? (1.0f / 128.0f) : (2.0f / 128.0f);
      float* o = ws + OFF_CS + f * 16;
      #pragma unroll
      for (int m = 0; m < EMB; ++m) { o[m] = ca[m] * wf; o[8 + m] = sa[m] * wf; }
    }
  }
  if (bid == 0 && tid < 64) {           // f = 8192: cos = (-1)^t, sin = 0
    int m = tid & 7, g = tid >> 3;
    float p = 0.f;
    #pragma unroll 8
    for (int j = 0; j < 64; ++j) p += e10T[m * 512 + g + 8 * j];
    p = (g & 1) ? -p : p;
    p += __shfl_xor(p, 8, 64);
    p += __shfl_xor(p, 16, 64);
    p += __shfl_xor(p, 32, 64);
    if (g == 0) {
      ws[OFF_CS + 8192 * 16 + m] = p * (1.0f / 128.0f);
      ws[OFF_CS + 8192 * 16 + 8 + m] = 0.f;
    }
  }
}

// ---------------- kernel 2: fused FFT1 + FFT2 + fourierGC + partial reduce ----------------
// 1024 threads, 4 f1 per block, grid (32,16); 2 blocks/CU -> 32 waves/CU
// LDS: xf[16416] (64.1KB, overlaid by Xs/red after fft1) + Gs[528] f2 (4.1KB)
#define XPAD(t) ((t) + ((t) >> 9))     // addr = n*513 + l  (bank-safe both ways)
__global__ __launch_bounds__(1024, 8)
void k_gcf(const float* __restrict__ x, const float* __restrict__ emb,
           const float* __restrict__ w0, const float* __restrict__ b0,
           const float* __restrict__ w1, const float* __restrict__ b1,
           const float* __restrict__ w2, const float* __restrict__ b2,
           float* __restrict__ ws) {
  __shared__ __align__(16) float xf[16416];
  __shared__ __align__(16) float2 Gs[4 * 132];  // quarter-skewed (stride 33)
  float2* Xs = (float2*)xf;                      // 257 float2 (xf dead then)
  float* red = xf + 1024;                        // 7*1024 (disjoint from Xs)
  int f1g = blockIdx.x, b = blockIdx.y, tid = threadIdx.x;
  int f1base = f1g * 4;
  // stage x[b,:] -> xf[t], t = n*512+l, padded; coalesced global reads
  {
    const float* xb = x + b * (Lseq * Nfeat);
    #pragma unroll
    for (int i = tid; i < Lseq * Nfeat; i += 1024) {
      int l = i >> 5, n = i & 31;
      xf[n * 513 + l] = xb[i];
    }
  }
  __syncthreads();
  // ----- FFT pass 1 (in-block): G[f1loc][t1] = tw(f1 t1) sum_t2 xf[t1+128 t2] W128^{f1 t2}
  if (tid < 512) {
    int f1loc = tid >> 7, t1 = tid & 127;
    int f1 = f1base + f1loc;
    float s1 = sin_rev((float)f1 * REV_128), c1 = cos_rev((float)f1 * REV_128);
    float c2 = c1 * c1 - s1 * s1, s2 = 2.f * s1 * c1;
    float cA = 1.f, sA = 0.f, cB = c1, sB = s1;
    float grA = 0.f, giA = 0.f, grB = 0.f, giB = 0.f;
    #pragma unroll 8
    for (int t2 = 0; t2 < 128; t2 += 2) {
      int ta = t1 + 128 * t2;
      float x0 = xf[XPAD(ta)], x1 = xf[XPAD(ta + 128)];
      grA = fmaf(x0, cA, grA); giA = fmaf(x0, -sA, giA);
      grB = fmaf(x1, cB, grB); giB = fmaf(x1, -sB, giB);
      float cn = cA * c2 - sA * s2; sA = sA * c2 + cA * s2; cA = cn;
      cn = cB * c2 - sB * s2;       sB = sB * c2 + cB * s2; cB = cn;
    }
    float gr = grA + grB, gi = giA + giB;
    float rv = (float)(f1 * t1) * REV_M;           // f1*t1 < 16384
    float sb = sin_rev(rv), cb = cos_rev(rv);
    Gs[f1loc * 132 + (t1 >> 5) * 33 + (t1 & 31)] =
        make_float2(gr * cb + gi * sb, gi * cb - gr * sb);
  }
  __syncthreads();
  // ----- phase A: X[f1+128 f2] via 32-tap quarters + shfl combine
  {
    int w = tid >> 6, lane = tid & 63;
    int f1loc = w >> 2;
    int q = lane >> 4, f2 = ((w & 3) << 4) + (lane & 15);
    int r = (f2 * q) & 3;               // start angle f2*q/4 rev: exact
    float c = (r == 0) ? 1.f : (r == 2) ? -1.f : 0.f;
    float s = (r == 1) ? 1.f : (r == 3) ? -1.f : 0.f;
    float s1 = sin_rev((float)f2 * REV_128), c1 = cos_rev((float)f2 * REV_128);
    float xr = 0.f, xi = 0.f;
    const float2* g = Gs + f1loc * 132 + q * 33;
    #pragma unroll 8
    for (int k = 0; k < 32; ++k) {
      float2 gv = g[k];
      xr = fmaf(gv.x, c, xr); xr = fmaf(gv.y, s, xr);
      xi = fmaf(gv.y, c, xi); xi = fmaf(-gv.x, s, xi);
      float cn = c * c1 - s * s1; s = s * c1 + c * s1; c = cn;
    }
    xr += __shfl_xor(xr, 16, 64); xi += __shfl_xor(xi, 16, 64);
    xr += __shfl_xor(xr, 32, 64); xi += __shfl_xor(xi, 32, 64);
    if (lane < 16) Xs[f1loc * 64 + f2] = make_float2(xr, xi);
    if (f1base == 0 && tid < 64) {      // f=8192: X = sum (-1)^t1 G[0][t1]
      int t1v = tid * 2;
      const float2* g0p = Gs + (t1v >> 5) * 33;
      float2 g0 = g0p[t1v & 31], g1 = g0p[(t1v & 31) + 1];
      float er = g0.x - g1.x, ei = g0.y - g1.y;
      #pragma unroll
      for (int off = 1; off <= 32; off <<= 1) {
        er += __shfl_xor(er, off, 64);
        ei += __shfl_xor(ei, off, 64);
      }
      if (tid == 0) Xs[256] = make_float2(er, ei);
    }
  }
  __syncthreads();
  // ----- phase B: GC chain + CS-weighted reduce; f split 8 ways
  int e = tid & 127, fh = tid >> 7;     // fh in [0,8)
  int nf = (f1base == 0) ? 257 : 256;
  float se  = emb[e] * (1.0f / 128.0f); // ortho forward scale
  float d00 = w0[e * 129], d01 = w0[E * E + e * 129];
  float c00 = b0[e],       c01 = b0[E + e];
  float d10 = w1[e * 129], d11 = w1[E * E + e * 129];
  float c10 = b1[e],       c11 = b1[E + e];
  float d20 = w2[e * 129], d21 = w2[E * E + e * 129];
  float c20 = b2[e],       c21 = b2[E + e];
  float acc[EMB];
  #pragma unroll
  for (int m = 0; m < EMB; ++m) acc[m] = 0.f;

  for (int i = fh; i < nf; i += 8) {
    int iu = __builtin_amdgcn_readfirstlane(i);     // wave-uniform -> SGPR
    int f = (iu == 256) ? 8192 : (f1base + (iu >> 6) + ((iu & 63) << 7));
    const float* cs = ws + OFF_CS + f * 16;         // scalar (s_load) path
    float2 X = Xs[iu];
    float xr = X.x * se, xi = X.y * se;
    float or0 = fmaxf(fmaf(xr, d00, fmaf(-xi, d01, c00)), 0.f);
    float oi0 = fmaxf(fmaf(xi, d00, fmaf(xr, d01, c01)), 0.f);
    float pr = fmaxf(or0 - LAMBDA, 0.f), pi = fmaxf(oi0 - LAMBDA, 0.f);
    float or1 = fmaxf(fmaf(or0, d10, fmaf(-oi0, d11, c10)), 0.f);
    float oi1 = fmaxf(fmaf(oi0, d10, fmaf(or1, d11, c11)), 0.f);
    pr += fmaxf(or1 - LAMBDA, 0.f); pi += fmaxf(oi1 - LAMBDA, 0.f);
    float u2r = fmaf(or1, d20, fmaf(-oi1, d21, c20));
    float or2 = fmaxf(u2r, 0.f);
    float u2i = fmaf(oi1, d20, fmaf(or2, d21, c21));
    float zr = fmaxf(u2r - LAMBDA, 0.f) + pr;       // shrink(relu(u)) = max(u-l,0)
    float zi = fmaxf(u2i - LAMBDA, 0.f) + pi;
    #pragma unroll
    for (int m = 0; m < EMB; ++m)
      acc[m] = fmaf(zr, cs[m], fmaf(-zi, cs[8 + m], acc[m]));
  }
  __syncthreads();
  if (fh > 0) {
    #pragma unroll
    for (int m = 0; m < EMB; ++m) red[(fh - 1) * 1024 + e * EMB + m] = acc[m];
  }
  __syncthreads();
  if (fh == 0) {
    #pragma unroll
    for (int j = 0; j < 7; ++j)
      #pragma unroll
      for (int m = 0; m < EMB; ++m) acc[m] += red[j * 1024 + e * EMB + m];
    float* P = ws + OFF_P + (f1g * 16 + b) * (E * EMB) + e * EMB;
    #pragma unroll
    for (int m = 0; m < EMB; ++m) P[m] = acc[m];
  }
}

// ---------------- kernel 3: P-reduce (32 chunks) + bias skip + FC head ----------------
__global__ __launch_bounds__(1024)
void k_fc(const float* __restrict__ x, const float* __restrict__ emb,
          const float* __restrict__ emb10,
          const float* __restrict__ fc1w, const float* __restrict__ fc1b,
          const float* __restrict__ fc2w, const float* __restrict__ fc2b,
          const float* __restrict__ fc3w, const float* __restrict__ fc3b,
          const float* __restrict__ ws, float* __restrict__ out) {
  int b = blockIdx.x;                   // grid 16
  __shared__ float h0s[E * EMB];
  __shared__ float h1s[FCH];
  __shared__ float h2s[Hd];
  __shared__ float hxs[EMB];
  __shared__ float scratch[1024];
  int tid = threadIdx.x;
  int lane = tid & 63, w = tid >> 6;    // 16 waves
  {
    int m = tid & 7, g = tid >> 3;      // 128 groups x 8 m
    float p = 0.f;
    #pragma unroll
    for (int l = g; l < Lseq; l += 128)
      p = fmaf(x[b * (Lseq * Nfeat) + l * Nfeat], emb10[l * EMB + m], p);
    scratch[tid] = p;
  }
  // P-reduce: thread owns k = tid, 32 chunks of stride 16*1024
  const float* P = ws + OFF_P + b * (E * EMB) + tid;
  float a = 0.f;
  #pragma unroll
  for (int c = 0; c < 32; ++c) a += P[c * (Bsz * E * EMB)];
  __syncthreads();
  if (tid < 8) {
    float s = 0.f;
    #pragma unroll 16
    for (int g = 0; g < 128; ++g) s += scratch[g * 8 + tid];
    hxs[tid] = s;
  }
  __syncthreads();
  h0s[tid] = a + emb[tid >> 3] * hxs[tid & 7];
  __syncthreads();
  // fc1: 64 outputs, K=1024; wave-per-output (coalesced weights)
  #pragma unroll
  for (int oo = 0; oo < 4; ++oo) {
    int o = oo * 16 + w;
    const float* wr = fc1w + o * (E * EMB);
    float acc = 0.f;
    #pragma unroll
    for (int j = 0; j < 16; ++j) acc = fmaf(h0s[lane + 64 * j], wr[lane + 64 * j], acc);
    #pragma unroll
    for (int off = 32; off >= 1; off >>= 1) acc += __shfl_xor(acc, off, 64);
    if (lane == 0) { float v = acc + fc1b[o]; h1s[o] = v > 0.f ? v : 0.01f * v; }
  }
  __syncthreads();
  // fc2: 256 outputs, K=64
  #pragma unroll
  for (int oo = 0; oo < 16; ++oo) {
    int o = oo * 16 + w;
    float acc = h1s[lane] * fc2w[o * FCH + lane];
    #pragma unroll
    for (int off = 32; off >= 1; off >>= 1) acc += __shfl_xor(acc, off, 64);
    if (lane == 0) { float v = acc + fc2b[o]; h2s[o] = v > 0.f ? v : 0.01f * v; }
  }
  __syncthreads();
  // fc3: 96 outputs, K=256
  #pragma unroll
  for (int oo = 0; oo < 6; ++oo) {
    int o = oo * 16 + w;
    const float* wr = fc3w + o * Hd;
    float acc = 0.f;
    #pragma unroll
    for (int j = 0; j < 4; ++j) acc = fmaf(h2s[lane + 64 * j], wr[lane + 64 * j], acc);
    #pragma unroll
    for (int off = 32; off >= 1; off >>= 1) acc += __shfl_xor(acc, off, 64);
    if (lane == 0) out[b * PRE + o] = acc + fc3b[o];
  }
}

extern "C" void kernel_launch(void* const* d_in, const int* in_sizes, int n_in,
                              void* d_out, int out_size, void* d_ws, size_t ws_size,
                              hipStream_t stream) {
  const float* x     = (const float*)d_in[0];
  const float* emb   = (const float*)d_in[1];
  const float* w0    = (const float*)d_in[2];
  const float* b0    = (const float*)d_in[3];
  const float* w1    = (const float*)d_in[4];
  const float* b1    = (const float*)d_in[5];
  const float* w2    = (const float*)d_in[6];
  const float* b2    = (const float*)d_in[7];
  const float* emb10 = (const float*)d_in[8];
  const float* fc1w  = (const float*)d_in[9];
  const float* fc1b  = (const float*)d_in[10];
  const float* fc2w  = (const float*)d_in[11];
  const float* fc2b  = (const float*)d_in[12];
  const float* fc3w  = (const float*)d_in[13];
  const float* fc3b  = (const float*)d_in[14];
  float* ws  = (float*)d_ws;
  float* out = (float*)d_out;

  k_cs<<<dim3(256), 256, 0, stream>>>(emb10, ws);
  k_gcf<<<dim3(32, Bsz), 1024, 0, stream>>>(x, emb, w0, b0, w1, b1, w2, b2, ws);
  k_fc<<<dim3(Bsz), 1024, 0, stream>>>(x, emb, emb10, fc1w, fc1b, fc2w, fc2b,
                                       fc3w, fc3b, ws, out);
}